// Round 1
// baseline (1886.957 us; speedup 1.0000x reference)
//
#include <hip/hip_runtime.h>

#define TT 2048
#define BB 8
#define DD 1024
#define NN 64

__device__ __forceinline__ float sigmoidf_(float x) {
    return 1.0f / (1.0f + __expf(-x));
}

// ---------------------------------------------------------------------------
// Phase 1: projections. C[m,n] = sum_d x[m,d] * W[n,d]  (m = t*B+b, n in [0,64))
// grid = (M/64, 4 matrices), block = 256. 64x64 tile, BK=32, 4x4 micro-tile.
// Matrix 3 (alpha) gets sigmoid(c + b_alpha[n]) fused in the epilogue.
// ---------------------------------------------------------------------------
__global__ __launch_bounds__(256) void proj_gemm_kernel(
    const float* __restrict__ x,
    const float* __restrict__ W0, const float* __restrict__ W1,
    const float* __restrict__ W2, const float* __restrict__ W3,
    const float* __restrict__ b_alpha,
    float* __restrict__ O0, float* __restrict__ O1,
    float* __restrict__ O2, float* __restrict__ O3)
{
    const int mat = blockIdx.y;
    const float* __restrict__ W = (mat == 0) ? W0 : (mat == 1) ? W1 : (mat == 2) ? W2 : W3;
    float* __restrict__ C       = (mat == 0) ? O0 : (mat == 1) ? O1 : (mat == 2) ? O2 : O3;

    const int m0  = blockIdx.x * 64;
    const int tid = threadIdx.x;
    const int tx  = tid & 15;   // output col group (n = tx*4 .. +3)
    const int ty  = tid >> 4;   // output row group (m = m0 + ty*4 .. +3)

    // Transposed tiles: xs[kk][m], ws[kk][n]. Pad 68 keeps float4 reads
    // 16B-aligned (68*4 = 272 = 16*17) and inner-loop reads conflict-light.
    __shared__ float xs[32][68];
    __shared__ float ws[32][68];

    float acc[4][4] = {};

    const int r  = tid >> 3;        // 0..31 (staging row)
    const int c4 = (tid & 7) * 4;   // 0..28 (staging col quad)

    for (int k0 = 0; k0 < DD; k0 += 32) {
        #pragma unroll
        for (int rr = 0; rr < 2; rr++) {
            const int row = r + rr * 32;
            float4 vx = *(const float4*)&x[(size_t)(m0 + row) * DD + k0 + c4];
            xs[c4 + 0][row] = vx.x;
            xs[c4 + 1][row] = vx.y;
            xs[c4 + 2][row] = vx.z;
            xs[c4 + 3][row] = vx.w;
            float4 vw = *(const float4*)&W[(size_t)row * DD + k0 + c4];
            ws[c4 + 0][row] = vw.x;
            ws[c4 + 1][row] = vw.y;
            ws[c4 + 2][row] = vw.z;
            ws[c4 + 3][row] = vw.w;
        }
        __syncthreads();

        #pragma unroll
        for (int kk = 0; kk < 32; kk++) {
            float4 av = *(const float4*)&xs[kk][ty * 4];
            float4 bv = *(const float4*)&ws[kk][tx * 4];
            float a[4] = {av.x, av.y, av.z, av.w};
            float e[4] = {bv.x, bv.y, bv.z, bv.w};
            #pragma unroll
            for (int i = 0; i < 4; i++)
                #pragma unroll
                for (int j = 0; j < 4; j++)
                    acc[i][j] = fmaf(a[i], e[j], acc[i][j]);
        }
        __syncthreads();
    }

    if (mat == 3) {
        #pragma unroll
        for (int j = 0; j < 4; j++) {
            const float ba = b_alpha[tx * 4 + j];
            #pragma unroll
            for (int i = 0; i < 4; i++)
                acc[i][j] = sigmoidf_(acc[i][j] + ba);
        }
    }

    #pragma unroll
    for (int i = 0; i < 4; i++) {
        *(float4*)&C[(size_t)(m0 + ty * 4 + i) * NN + tx * 4] =
            make_float4(acc[i][0], acc[i][1], acc[i][2], acc[i][3]);
    }
}

// ---------------------------------------------------------------------------
// Phase 2: sequential scan. grid = B (8 blocks), block = 256 (4 waves).
// Wave w owns rows [16w, 16w+16); lane quad (4 lanes) per row, 16 cols/lane.
// S kept entirely in registers; row reductions via in-wave shfl_xor; no
// __syncthreads anywhere in the T loop. Distance-1 prefetch of k/q/v/alpha.
// ---------------------------------------------------------------------------
__global__ __launch_bounds__(256) void scan_kernel(
    const float* __restrict__ k_all, const float* __restrict__ v_all,
    const float* __restrict__ q_all, const float* __restrict__ a_all,
    const float* __restrict__ S0,
    const float* __restrict__ d_g, const float* __restrict__ b_g,
    float* __restrict__ out, float* __restrict__ S_final)
{
    const int b    = blockIdx.x;
    const int tid  = threadIdx.x;
    const int lane = tid & 63;
    const int wave = tid >> 6;
    const int row  = wave * 16 + (lane >> 2);  // 0..63
    const int cs   = (lane & 3) * 16;          // col start, 0/16/32/48

    float S[16];
    #pragma unroll
    for (int c = 0; c < 16; c += 4) {
        float4 v = *(const float4*)&S0[((size_t)b * NN + row) * NN + cs + c];
        S[c] = v.x; S[c + 1] = v.y; S[c + 2] = v.z; S[c + 3] = v.w;
    }
    const float dg = d_g[row];
    const float bg = b_g[row];

    const int stride = BB * NN;  // 512 floats per t-step
    const float* kp = k_all + b * NN + cs;
    const float* qp = q_all + b * NN + cs;
    const float* vp = v_all + b * NN + row;
    const float* ap = a_all + b * NN + row;

    // prefetch t=0
    float4 kn[4], qn[4];
    float vn, an;
    #pragma unroll
    for (int c = 0; c < 4; c++) {
        kn[c] = *(const float4*)(kp + 4 * c);
        qn[c] = *(const float4*)(qp + 4 * c);
    }
    vn = *vp; an = *ap;

    float* op = out + b * NN + row;

    for (int t = 0; t < TT; t++) {
        float kc[16], qc[16];
        #pragma unroll
        for (int c = 0; c < 4; c++) {
            kc[4*c+0] = kn[c].x; kc[4*c+1] = kn[c].y; kc[4*c+2] = kn[c].z; kc[4*c+3] = kn[c].w;
            qc[4*c+0] = qn[c].x; qc[4*c+1] = qn[c].y; qc[4*c+2] = qn[c].z; qc[4*c+3] = qn[c].w;
        }
        const float vc = vn, ac = an;

        // prefetch t+1 (arrays padded by one step in ws; final prefetch unused)
        kp += stride; qp += stride; vp += stride; ap += stride;
        #pragma unroll
        for (int c = 0; c < 4; c++) {
            kn[c] = *(const float4*)(kp + 4 * c);
            qn[c] = *(const float4*)(qp + 4 * c);
        }
        vn = *vp; an = *ap;

        // retrieved = (S @ k)[row], 4-way accumulator ILP + quad reduce
        float r0 = 0.f, r1 = 0.f, r2 = 0.f, r3 = 0.f;
        #pragma unroll
        for (int c = 0; c < 16; c += 4) {
            r0 = fmaf(S[c],     kc[c],     r0);
            r1 = fmaf(S[c + 1], kc[c + 1], r1);
            r2 = fmaf(S[c + 2], kc[c + 2], r2);
            r3 = fmaf(S[c + 3], kc[c + 3], r3);
        }
        float rv = (r0 + r1) + (r2 + r3);
        rv += __shfl_xor(rv, 1, 64);
        rv += __shfl_xor(rv, 2, 64);

        const float g    = sigmoidf_(fmaf(dg, rv, bg));
        const float coef = (1.0f - ac) * (vc * g);

        // S update + out = (S_new @ q)[row] fused in one pass
        float o0 = 0.f, o1 = 0.f, o2 = 0.f, o3 = 0.f;
        #pragma unroll
        for (int c = 0; c < 16; c += 4) {
            S[c]     = fmaf(ac, S[c],     coef * kc[c]);
            S[c + 1] = fmaf(ac, S[c + 1], coef * kc[c + 1]);
            S[c + 2] = fmaf(ac, S[c + 2], coef * kc[c + 2]);
            S[c + 3] = fmaf(ac, S[c + 3], coef * kc[c + 3]);
            o0 = fmaf(S[c],     qc[c],     o0);
            o1 = fmaf(S[c + 1], qc[c + 1], o1);
            o2 = fmaf(S[c + 2], qc[c + 2], o2);
            o3 = fmaf(S[c + 3], qc[c + 3], o3);
        }
        float ov = (o0 + o1) + (o2 + o3);
        ov += __shfl_xor(ov, 1, 64);
        ov += __shfl_xor(ov, 2, 64);

        const float y = ov * ov * sigmoidf_(ov);  // out * silu(out)
        if ((lane & 3) == 0) *op = y;
        op += stride;
    }

    #pragma unroll
    for (int c = 0; c < 16; c += 4) {
        *(float4*)&S_final[((size_t)b * NN + row) * NN + cs + c] =
            make_float4(S[c], S[c + 1], S[c + 2], S[c + 3]);
    }
}

// ---------------------------------------------------------------------------
extern "C" void kernel_launch(void* const* d_in, const int* in_sizes, int n_in,
                              void* d_out, int out_size, void* d_ws, size_t ws_size,
                              hipStream_t stream) {
    const float* x       = (const float*)d_in[0];
    const float* S0      = (const float*)d_in[1];
    const float* W_k     = (const float*)d_in[2];
    const float* W_v     = (const float*)d_in[3];
    const float* W_q     = (const float*)d_in[4];
    const float* W_alpha = (const float*)d_in[5];
    const float* b_alpha = (const float*)d_in[6];
    const float* d_g     = (const float*)d_in[7];
    const float* b_g     = (const float*)d_in[8];
    float* out = (float*)d_out;

    // ws layout: 4 arrays of (TT+1)*BB*NN floats (one extra step of padding so
    // the scan's distance-1 prefetch never reads outside d_ws). ~16.8 MB total.
    const size_t arr = (size_t)(TT + 1) * BB * NN;
    float* ws    = (float*)d_ws;
    float* k_all = ws;
    float* v_all = ws + arr;
    float* q_all = ws + 2 * arr;
    float* a_all = ws + 3 * arr;

    proj_gemm_kernel<<<dim3(TT * BB / 64, 4), 256, 0, stream>>>(
        x, W_k, W_v, W_q, W_alpha, b_alpha, k_all, v_all, q_all, a_all);

    scan_kernel<<<dim3(BB), 256, 0, stream>>>(
        k_all, v_all, q_all, a_all, S0, d_g, b_g,
        out, out + (size_t)TT * BB * NN);
}

// Round 2
// 847.783 us; speedup vs baseline: 2.2258x; 2.2258x over previous
//
#include <hip/hip_runtime.h>

#define TT 2048
#define BB 8
#define DD 1024
#define NN 64
#define CH 32              // timesteps staged per LDS chunk
#define NCH (TT / CH)

__device__ __forceinline__ float sigmoidf_(float x) {
    return 1.0f / (1.0f + __expf(-x));
}

// quad_perm DPP cross-lane (pure VALU, no lgkmcnt): xor1 = [1,0,3,2] = 0xB1,
// xor2 = [2,3,0,1] = 0x4E. Valid because each row uses exactly one lane-quad.
__device__ __forceinline__ float quad_xor1(float x) {
    return __int_as_float(__builtin_amdgcn_update_dpp(
        0, __float_as_int(x), 0xB1, 0xF, 0xF, true));
}
__device__ __forceinline__ float quad_xor2(float x) {
    return __int_as_float(__builtin_amdgcn_update_dpp(
        0, __float_as_int(x), 0x4E, 0xF, 0xF, true));
}

// async global->LDS, 16 B/lane. LDS dest is wave-uniform base + lane*16.
__device__ __forceinline__ void gll16(const float* g, float* l) {
    __builtin_amdgcn_global_load_lds(
        (const __attribute__((address_space(1))) void*)g,
        (__attribute__((address_space(3))) void*)l, 16, 0, 0);
}

// ---------------------------------------------------------------------------
// Phase 1: projections. C[m,n] = sum_d x[m,d] * W[n,d]
// grid = (M/64, 4), block 256. 64x64 tile, BK=32, 4x4 micro-tile.
// Staging register-prefetched one K-slab ahead so HBM latency overlaps FMAs.
// ---------------------------------------------------------------------------
__global__ __launch_bounds__(256) void proj_gemm_kernel(
    const float* __restrict__ x,
    const float* __restrict__ W0, const float* __restrict__ W1,
    const float* __restrict__ W2, const float* __restrict__ W3,
    const float* __restrict__ b_alpha,
    float* __restrict__ O0, float* __restrict__ O1,
    float* __restrict__ O2, float* __restrict__ O3)
{
    const int mat = blockIdx.y;
    const float* __restrict__ W = (mat == 0) ? W0 : (mat == 1) ? W1 : (mat == 2) ? W2 : W3;
    float* __restrict__ C       = (mat == 0) ? O0 : (mat == 1) ? O1 : (mat == 2) ? O2 : O3;

    const int m0  = blockIdx.x * 64;
    const int tid = threadIdx.x;
    const int tx  = tid & 15;
    const int ty  = tid >> 4;

    __shared__ float xs[32][68];
    __shared__ float ws[32][68];

    float acc[4][4] = {};

    const int r  = tid >> 3;
    const int c4 = (tid & 7) * 4;

    float4 px[2], pw[2];
    #pragma unroll
    for (int rr = 0; rr < 2; rr++) {
        const int row = r + rr * 32;
        px[rr] = *(const float4*)&x[(size_t)(m0 + row) * DD + c4];
        pw[rr] = *(const float4*)&W[(size_t)row * DD + c4];
    }

    for (int k0 = 0; k0 < DD; k0 += 32) {
        #pragma unroll
        for (int rr = 0; rr < 2; rr++) {
            const int row = r + rr * 32;
            xs[c4 + 0][row] = px[rr].x;
            xs[c4 + 1][row] = px[rr].y;
            xs[c4 + 2][row] = px[rr].z;
            xs[c4 + 3][row] = px[rr].w;
            ws[c4 + 0][row] = pw[rr].x;
            ws[c4 + 1][row] = pw[rr].y;
            ws[c4 + 2][row] = pw[rr].z;
            ws[c4 + 3][row] = pw[rr].w;
        }
        if (k0 + 32 < DD) {
            #pragma unroll
            for (int rr = 0; rr < 2; rr++) {
                const int row = r + rr * 32;
                px[rr] = *(const float4*)&x[(size_t)(m0 + row) * DD + k0 + 32 + c4];
                pw[rr] = *(const float4*)&W[(size_t)row * DD + k0 + 32 + c4];
            }
        }
        __syncthreads();

        #pragma unroll
        for (int kk = 0; kk < 32; kk++) {
            float4 av = *(const float4*)&xs[kk][ty * 4];
            float4 bv = *(const float4*)&ws[kk][tx * 4];
            float a[4] = {av.x, av.y, av.z, av.w};
            float e[4] = {bv.x, bv.y, bv.z, bv.w};
            #pragma unroll
            for (int i = 0; i < 4; i++)
                #pragma unroll
                for (int j = 0; j < 4; j++)
                    acc[i][j] = fmaf(a[i], e[j], acc[i][j]);
        }
        __syncthreads();
    }

    if (mat == 3) {
        #pragma unroll
        for (int j = 0; j < 4; j++) {
            const float ba = b_alpha[tx * 4 + j];
            #pragma unroll
            for (int i = 0; i < 4; i++)
                acc[i][j] = sigmoidf_(acc[i][j] + ba);
        }
    }

    #pragma unroll
    for (int i = 0; i < 4; i++) {
        *(float4*)&C[(size_t)(m0 + ty * 4 + i) * NN + tx * 4] =
            make_float4(acc[i][0], acc[i][1], acc[i][2], acc[i][3]);
    }
}

// ---------------------------------------------------------------------------
// Phase 2: scan. grid = B, block 256 (4 waves, 16 rows/wave, 4 lanes/row).
// k/q/v/alpha staged in LDS 32 steps at a time, double-buffered, loaded with
// global_load_lds issued one full chunk ahead (drained by the chunk barrier).
// Inside a chunk: distance-1 register prefetch from LDS; DPP quad reductions.
// ---------------------------------------------------------------------------
__global__ __launch_bounds__(256) void scan_kernel(
    const float* __restrict__ k_all, const float* __restrict__ v_all,
    const float* __restrict__ q_all, const float* __restrict__ a_all,
    const float* __restrict__ S0,
    const float* __restrict__ d_g, const float* __restrict__ b_g,
    float* __restrict__ out, float* __restrict__ S_final)
{
    const int b    = blockIdx.x;
    const int tid  = threadIdx.x;
    const int lane = tid & 63;
    const int wave = tid >> 6;
    const int row  = wave * 16 + (lane >> 2);  // 0..63
    const int cs   = (lane & 3) * 16;          // col start

    __shared__ float ks[2][CH * NN];
    __shared__ float qs[2][CH * NN];
    __shared__ float vs[2][CH * NN];
    __shared__ float as_[2][CH * NN];          // 64 KB total

    float S[16];
    #pragma unroll
    for (int c = 0; c < 16; c += 4) {
        float4 v = *(const float4*)&S0[((size_t)b * NN + row) * NN + cs + c];
        S[c] = v.x; S[c + 1] = v.y; S[c + 2] = v.z; S[c + 3] = v.w;
    }
    const float dg = d_g[row];
    const float bg = b_g[row];

    const int stride = BB * NN;

    // wave w stages steps [w*8, w*8+8) of a chunk; 4 steps per gll instr
    // (64 lanes x 16B = 1KB = 4 steps x 256B), 2 instrs per array per wave.
    const int t_lane = lane >> 4;        // 0..3: step within the 4-step group
    const int f_lane = (lane & 15) * 4;  // 0..60: float4 column

    auto stage = [&](int chunk, int dbuf) {
        #pragma unroll
        for (int j = 0; j < 2; ++j) {
            const int s0 = wave * 8 + j * 4;
            const size_t t = (size_t)chunk * CH + s0 + t_lane;
            const size_t goff = (t * BB + b) * NN + f_lane;
            const int loff = s0 * NN;
            gll16(k_all + goff, &ks[dbuf][loff]);
            gll16(q_all + goff, &qs[dbuf][loff]);
            gll16(v_all + goff, &vs[dbuf][loff]);
            gll16(a_all + goff, &as_[dbuf][loff]);
        }
    };

    stage(0, 0);

    float* op = out + b * NN + row;

    for (int c = 0; c < NCH; ++c) {
        const int cb = c & 1;
        // barrier: (a) chunk c's gll complete (vmcnt drained per-wave before
        // s_barrier), (b) all waves done reading buf cb^1 from chunk c-1.
        __syncthreads();
        if (c + 1 < NCH) stage(c + 1, cb ^ 1);

        const float* kb = ks[cb];
        const float* qb = qs[cb];
        const float* vb = vs[cb];
        const float* ab = as_[cb];

        // step-0 registers
        float4 kc4[4], qc4[4];
        #pragma unroll
        for (int i = 0; i < 4; i++) {
            kc4[i] = *(const float4*)&kb[cs + 4 * i];
            qc4[i] = *(const float4*)&qb[cs + 4 * i];
        }
        float vc = vb[row];
        float ac = ab[row];

        #pragma unroll 4
        for (int s = 0; s < CH; ++s) {
            // distance-1 LDS prefetch (wraps to step 0 on last iter; discarded)
            const int sn = (s + 1) & (CH - 1);
            float4 kn4[4], qn4[4];
            #pragma unroll
            for (int i = 0; i < 4; i++) {
                kn4[i] = *(const float4*)&kb[sn * NN + cs + 4 * i];
                qn4[i] = *(const float4*)&qb[sn * NN + cs + 4 * i];
            }
            const float vn = vb[sn * NN + row];
            const float an = ab[sn * NN + row];

            float kc[16], qc[16];
            #pragma unroll
            for (int i = 0; i < 4; i++) {
                kc[4*i+0] = kc4[i].x; kc[4*i+1] = kc4[i].y;
                kc[4*i+2] = kc4[i].z; kc[4*i+3] = kc4[i].w;
                qc[4*i+0] = qc4[i].x; qc[4*i+1] = qc4[i].y;
                qc[4*i+2] = qc4[i].z; qc[4*i+3] = qc4[i].w;
            }

            // retrieved = (S @ k)[row]
            float r0 = 0.f, r1 = 0.f, r2 = 0.f, r3 = 0.f;
            #pragma unroll
            for (int e = 0; e < 16; e += 4) {
                r0 = fmaf(S[e],     kc[e],     r0);
                r1 = fmaf(S[e + 1], kc[e + 1], r1);
                r2 = fmaf(S[e + 2], kc[e + 2], r2);
                r3 = fmaf(S[e + 3], kc[e + 3], r3);
            }
            float rv = (r0 + r1) + (r2 + r3);
            rv += quad_xor1(rv);
            rv += quad_xor2(rv);

            const float g    = sigmoidf_(fmaf(dg, rv, bg));
            const float coef = (1.0f - ac) * (vc * g);

            // S update + out = (S_new @ q)[row]
            float o0 = 0.f, o1 = 0.f, o2 = 0.f, o3 = 0.f;
            #pragma unroll
            for (int e = 0; e < 16; e += 4) {
                S[e]     = fmaf(ac, S[e],     coef * kc[e]);
                S[e + 1] = fmaf(ac, S[e + 1], coef * kc[e + 1]);
                S[e + 2] = fmaf(ac, S[e + 2], coef * kc[e + 2]);
                S[e + 3] = fmaf(ac, S[e + 3], coef * kc[e + 3]);
                o0 = fmaf(S[e],     qc[e],     o0);
                o1 = fmaf(S[e + 1], qc[e + 1], o1);
                o2 = fmaf(S[e + 2], qc[e + 2], o2);
                o3 = fmaf(S[e + 3], qc[e + 3], o3);
            }
            float ov = (o0 + o1) + (o2 + o3);
            ov += quad_xor1(ov);
            ov += quad_xor2(ov);

            const float y = ov * ov * sigmoidf_(ov);  // out * silu(out)
            if ((lane & 3) == 0) *op = y;
            op += stride;

            // rotate prefetched regs
            #pragma unroll
            for (int i = 0; i < 4; i++) { kc4[i] = kn4[i]; qc4[i] = qn4[i]; }
            vc = vn; ac = an;
        }
    }

    #pragma unroll
    for (int c = 0; c < 16; c += 4) {
        *(float4*)&S_final[((size_t)b * NN + row) * NN + cs + c] =
            make_float4(S[c], S[c + 1], S[c + 2], S[c + 3]);
    }
}

// ---------------------------------------------------------------------------
extern "C" void kernel_launch(void* const* d_in, const int* in_sizes, int n_in,
                              void* d_out, int out_size, void* d_ws, size_t ws_size,
                              hipStream_t stream) {
    const float* x       = (const float*)d_in[0];
    const float* S0      = (const float*)d_in[1];
    const float* W_k     = (const float*)d_in[2];
    const float* W_v     = (const float*)d_in[3];
    const float* W_q     = (const float*)d_in[4];
    const float* W_alpha = (const float*)d_in[5];
    const float* b_alpha = (const float*)d_in[6];
    const float* d_g     = (const float*)d_in[7];
    const float* b_g     = (const float*)d_in[8];
    float* out = (float*)d_out;

    const size_t arr = (size_t)TT * BB * NN;
    float* ws    = (float*)d_ws;
    float* k_all = ws;
    float* v_all = ws + arr;
    float* q_all = ws + 2 * arr;
    float* a_all = ws + 3 * arr;

    proj_gemm_kernel<<<dim3(TT * BB / 64, 4), 256, 0, stream>>>(
        x, W_k, W_v, W_q, W_alpha, b_alpha, k_all, v_all, q_all, a_all);

    scan_kernel<<<dim3(BB), 256, 0, stream>>>(
        k_all, v_all, q_all, a_all, S0, d_g, b_g,
        out, out + (size_t)TT * BB * NN);
}